// Round 11
// baseline (311.430 us; speedup 1.0000x reference)
//
#include <hip/hip_runtime.h>
#include <cstdint>

#define HIDDEN 2048
#define NHEADS 16
#define DH 128
#define BATCH 2
#define SEQ 2048
#define MTOT 4096
#define BH (BATCH * NHEADS)

typedef __attribute__((ext_vector_type(8))) short bf16x8;
typedef __attribute__((ext_vector_type(4))) float f32x4;

// SCALE * log2(e): scores come out of QK^T already in log2 domain
static constexpr float QSCALE = (float)(0.08838834764831845 * 1.4426950408889634);

__device__ __forceinline__ unsigned short f2bf(float f) {
  union { float f; uint32_t u; } v; v.f = f;
  uint32_t r = v.u + 0x7FFFu + ((v.u >> 16) & 1u);
  return (unsigned short)(r >> 16);
}
__device__ __forceinline__ uint32_t cvtpk(float lo, float hi) {
  uint32_t r;
  asm("v_cvt_pk_bf16_f32 %0, %1, %2" : "=v"(r) : "v"(lo), "v"(hi));
  return r;
}
__device__ __forceinline__ f32x4 mfma16(bf16x8 a, bf16x8 b, f32x4 c) {
  return __builtin_amdgcn_mfma_f32_16x16x32_bf16(a, b, c, 0, 0, 0);
}

typedef const __attribute__((address_space(1))) unsigned char* gas1_t;
typedef __attribute__((address_space(3))) unsigned char* las3_t;
__device__ __forceinline__ void gll16(const void* g, void* l) {
  __builtin_amdgcn_global_load_lds((gas1_t)g, (las3_t)l, 16, 0, 0);
}

// ---------------------------------------------------------------------------
// Fused cast: X (8.4M) + Wq/Wk/Wv/Wo (4.2M each), fp32 -> bf16, one launch.
// ---------------------------------------------------------------------------
__global__ __launch_bounds__(256) void cast_all(
    const float* __restrict__ X, const float* __restrict__ Wq,
    const float* __restrict__ Wk, const float* __restrict__ Wv,
    const float* __restrict__ Wo, unsigned short* __restrict__ Xb,
    unsigned short* __restrict__ Wqb, unsigned short* __restrict__ Wkb,
    unsigned short* __restrict__ Wvb, unsigned short* __restrict__ Wob) {
  const int n1 = MTOT * HIDDEN;           // 8388608
  const int i = (blockIdx.x * 256 + threadIdx.x) * 4;
  const float* s;
  unsigned short* d;
  int o;
  if (i < n1) {
    s = X; d = Xb; o = i;
  } else {
    const int j = i - n1;
    const int w = j >> 22;                 // n2 = 2^22
    o = j & ((1 << 22) - 1);
    s = (w == 0) ? Wq : (w == 1) ? Wk : (w == 2) ? Wv : Wo;
    d = (w == 0) ? Wqb : (w == 1) ? Wkb : (w == 2) ? Wvb : Wob;
  }
  float4 f = *(const float4*)&s[o];
  ushort4 u;
  u.x = f2bf(f.x); u.y = f2bf(f.y); u.z = f2bf(f.z); u.w = f2bf(f.w);
  *(ushort4*)&d[o] = u;
}

// ---------------------------------------------------------------------------
// 256x256 8-phase GEMM template (m201-style). BK=64, 512 thr / 8 waves
// (2M x 4N), per-wave 128x64 output: acc[8][4] f32x4 (42.7 FLOP/LDS-byte ->
// per-phase LDS reads < per-phase MFMA). LDS: 2 buffers x 64KB, each
// k-half-major: A @ {ks*16384 + row*64 + (j^(row&3))*16}, B same @ +32768.
// Per K-tile t (buffer t&1), 4 phases = (ks, mh), each:
//   {4-8 ds_read_b128 -> 2 gll16 (one 16KB half-stage) -> s_barrier ->
//    setprio(1) 16 MFMA setprio(0) -> s_barrier}
// B-frags held in regs across the two mh-phases of a ks.
// Rolling stage: ph1: A-k1(t+1)->other buf; ph2: B-k1(t+1)->other buf;
// ph3: A-k0(t+2)->this buf (k0 region retired at ph2 barrier);
// ph4: B-k0(t+2)->this buf. vmcnt(4) once per tile at end of ph4: the only
// outstanding loads are ph3/ph4's 4 -> everything needed for t+1 landed,
// pipe never drains until the 2-tile tail (vmcnt(0) at t=30, none at 31).
// Staging chunk c = wv*64+lane (+512): row=c>>2 (+128), j=(c&3)^(row&3) ->
// inverse-permuted global source, linear LDS dest (rule #21).
// ---------------------------------------------------------------------------
template <int VM, bool PF1, bool PF2>
__device__ __forceinline__ void tile_body(
    int t, char* SM, const unsigned short* pa, const unsigned short* pb,
    int wv, int wr, int wc, int g, int lr, f32x4 (&acc)[8][4]) {
  char* buf  = SM + (size_t)((t & 1) * 65536);
  char* obuf = SM + (size_t)(((t + 1) & 1) * 65536);
  const int swz16 = (g ^ (lr & 3)) * 16;
  const size_t ko1 = (size_t)(t + 1) * 64 + 32;  // k1 of tile t+1
  const size_t ko0 = (size_t)(t + 2) * 64;       // k0 of tile t+2
  const size_t rowskip = (size_t)128 * HIDDEN;
  bf16x8 a[4], b[4];

  // ---- phase 1: ks=0, mh=0 (loads B ks0) ----
#pragma unroll
  for (int mi = 0; mi < 4; ++mi)
    a[mi] = *(const bf16x8*)(buf + (wr * 128 + mi * 16 + lr) * 64 + swz16);
#pragma unroll
  for (int ni = 0; ni < 4; ++ni)
    b[ni] = *(const bf16x8*)(buf + 32768 + (wc * 64 + ni * 16 + lr) * 64 + swz16);
  if (PF1) {
    char* d = obuf + 16384 + wv * 1024;
    gll16(pa + ko1, d);
    gll16(pa + rowskip + ko1, d + 8192);
  }
  __builtin_amdgcn_s_barrier();
  __builtin_amdgcn_s_setprio(1);
#pragma unroll
  for (int mi = 0; mi < 4; ++mi)
#pragma unroll
    for (int ni = 0; ni < 4; ++ni)
      acc[mi][ni] = mfma16(a[mi], b[ni], acc[mi][ni]);
  __builtin_amdgcn_s_setprio(0);
  __builtin_amdgcn_s_barrier();

  // ---- phase 2: ks=0, mh=1 (B held) ----
#pragma unroll
  for (int mi = 0; mi < 4; ++mi)
    a[mi] = *(const bf16x8*)(buf + (wr * 128 + 64 + mi * 16 + lr) * 64 + swz16);
  if (PF1) {
    char* d = obuf + 32768 + 16384 + wv * 1024;
    gll16(pb + ko1, d);
    gll16(pb + rowskip + ko1, d + 8192);
  }
  __builtin_amdgcn_s_barrier();
  __builtin_amdgcn_s_setprio(1);
#pragma unroll
  for (int mi = 0; mi < 4; ++mi)
#pragma unroll
    for (int ni = 0; ni < 4; ++ni)
      acc[4 + mi][ni] = mfma16(a[mi], b[ni], acc[4 + mi][ni]);
  __builtin_amdgcn_s_setprio(0);
  __builtin_amdgcn_s_barrier();

  // ---- phase 3: ks=1, mh=0 (loads B ks1) ----
#pragma unroll
  for (int mi = 0; mi < 4; ++mi)
    a[mi] = *(const bf16x8*)(buf + 16384 + (wr * 128 + mi * 16 + lr) * 64 + swz16);
#pragma unroll
  for (int ni = 0; ni < 4; ++ni)
    b[ni] = *(const bf16x8*)(buf + 32768 + 16384 + (wc * 64 + ni * 16 + lr) * 64 + swz16);
  if (PF2) {
    char* d = buf + wv * 1024;  // k0 region of THIS buf: retired at ph2 barrier
    gll16(pa + ko0, d);
    gll16(pa + rowskip + ko0, d + 8192);
  }
  __builtin_amdgcn_s_barrier();
  __builtin_amdgcn_s_setprio(1);
#pragma unroll
  for (int mi = 0; mi < 4; ++mi)
#pragma unroll
    for (int ni = 0; ni < 4; ++ni)
      acc[mi][ni] = mfma16(a[mi], b[ni], acc[mi][ni]);
  __builtin_amdgcn_s_setprio(0);
  __builtin_amdgcn_s_barrier();

  // ---- phase 4: ks=1, mh=1; vmcnt once per K-tile ----
#pragma unroll
  for (int mi = 0; mi < 4; ++mi)
    a[mi] = *(const bf16x8*)(buf + 16384 + (wr * 128 + 64 + mi * 16 + lr) * 64 + swz16);
  if (PF2) {
    char* d = buf + 32768 + wv * 1024;
    gll16(pb + ko0, d);
    gll16(pb + rowskip + ko0, d + 8192);
  }
  __builtin_amdgcn_s_barrier();
  __builtin_amdgcn_s_setprio(1);
#pragma unroll
  for (int mi = 0; mi < 4; ++mi)
#pragma unroll
    for (int ni = 0; ni < 4; ++ni)
      acc[4 + mi][ni] = mfma16(a[mi], b[ni], acc[4 + mi][ni]);
  __builtin_amdgcn_s_setprio(0);
  if (VM == 4) asm volatile("s_waitcnt vmcnt(4)" ::: "memory");
  else if (VM == 0) asm volatile("s_waitcnt vmcnt(0)" ::: "memory");
  if (VM >= 0) __builtin_amdgcn_s_barrier();
}

#define PIPE256_SETUP(Abase, Bbase)                                           \
  const int c0 = wv * 64 + lane;                                              \
  const int row0 = c0 >> 2, j0 = (c0 & 3) ^ (row0 & 3);                       \
  const unsigned short* pa = (Abase) + (size_t)(m0 + row0) * HIDDEN + j0 * 8; \
  const unsigned short* pb = (Bbase) + (size_t)(n0 + row0) * HIDDEN + j0 * 8; \
  const size_t rsk = (size_t)128 * HIDDEN;

#define PIPE256_PROLOGUE()                                                    \
  {                                                                           \
    char* dA0 = SM + wv * 1024;                                               \
    gll16(pa + 0, dA0); gll16(pa + rsk + 0, dA0 + 8192);                      \
    char* dB0 = SM + 32768 + wv * 1024;                                       \
    gll16(pb + 0, dB0); gll16(pb + rsk + 0, dB0 + 8192);                      \
    char* dA1 = SM + 16384 + wv * 1024;                                       \
    gll16(pa + 32, dA1); gll16(pa + rsk + 32, dA1 + 8192);                    \
    char* dB1 = SM + 32768 + 16384 + wv * 1024;                               \
    gll16(pb + 32, dB1); gll16(pb + rsk + 32, dB1 + 8192);                    \
    char* eA0 = SM + 65536 + wv * 1024;                                       \
    gll16(pa + 64, eA0); gll16(pa + rsk + 64, eA0 + 8192);                    \
    char* eB0 = SM + 65536 + 32768 + wv * 1024;                               \
    gll16(pb + 64, eB0); gll16(pb + rsk + 64, eB0 + 8192);                    \
  }                                                                           \
  asm volatile("s_waitcnt vmcnt(4)" ::: "memory");                            \
  __builtin_amdgcn_s_barrier();

#define PIPE256_LOOP()                                                        \
  for (int t = 0; t < 30; ++t)                                                \
    tile_body<4, true, true>(t, SM, pa, pb, wv, wr, wc, g, lr, acc);          \
  tile_body<0, true, false>(30, SM, pa, pb, wv, wr, wc, g, lr, acc);          \
  tile_body<-1, false, false>(31, SM, pa, pb, wv, wr, wc, g, lr, acc);

// ---------------------------------------------------------------------------
// Fused Q/K/V projection, 256x256 tiles. grid (24, 16): which = x>>3,
// n0 = (x&7)*256 (x%8 pins n-panel to an XCD), m0 = y*256.
// which 0: Q [BH][S][D] (alpha=QSCALE); 1: K blocked [BH][S/32][d/8][s%32][8];
// 2: V blocked [BH][S/8][D][8].
// ---------------------------------------------------------------------------
__global__ __launch_bounds__(512) void gemm_qkv_pipe(
    const unsigned short* __restrict__ A, const unsigned short* __restrict__ Wq,
    const unsigned short* __restrict__ Wk, const unsigned short* __restrict__ Wv,
    unsigned short* __restrict__ Qb, unsigned short* __restrict__ Kb,
    unsigned short* __restrict__ Vb) {
  __shared__ __align__(16) char SM[131072];
  const int tid = threadIdx.x;
  const int lane = tid & 63, wv = tid >> 6;
  const int wr = wv >> 2, wc = wv & 3;
  const int g = lane >> 4, lr = lane & 15;
  const int which = blockIdx.x >> 3;
  const int m0 = blockIdx.y * 256, n0 = (blockIdx.x & 7) * 256;
  const unsigned short* W = (which == 0) ? Wq : (which == 1) ? Wk : Wv;

  PIPE256_SETUP(A, W)

  f32x4 acc[8][4];
#pragma unroll
  for (int i = 0; i < 8; ++i)
#pragma unroll
    for (int j = 0; j < 4; ++j) acc[i][j] = (f32x4){0.f, 0.f, 0.f, 0.f};

  PIPE256_PROLOGUE()
  PIPE256_LOOP()

  const float alpha = (which == 0) ? QSCALE : 1.0f;
  unsigned short* C = (which == 0) ? Qb : (which == 1) ? Kb : Vb;
#pragma unroll
  for (int mi = 0; mi < 8; ++mi)
#pragma unroll
    for (int ni = 0; ni < 4; ++ni)
#pragma unroll
      for (int r = 0; r < 4; ++r) {
        const int row = m0 + wr * 128 + mi * 16 + g * 4 + r;
        const int col = n0 + wc * 64 + ni * 16 + lr;
        const unsigned short v = f2bf(acc[mi][ni][r] * alpha);
        const int b = row >> 11, s = row & (SEQ - 1);
        const int h = col >> 7, d = col & (DH - 1);
        const size_t base = (size_t)(b * NHEADS + h) * SEQ * DH;
        if (which == 0)
          C[base + (size_t)s * DH + d] = v;
        else if (which == 1)
          C[base + (size_t)(s >> 5) * 4096 + (d >> 3) * 256 + (s & 31) * 8 + (d & 7)] = v;
        else
          C[base + (size_t)(s >> 3) * 1024 + d * 8 + (s & 7)] = v;
      }
}

// ---------------------------------------------------------------------------
// O-projection, 256x256 tiles: C(f32)[4096][2048] = A_bf16 @ Wo_bf16^T.
// grid (8, 16) = 128 blocks.
// ---------------------------------------------------------------------------
__global__ __launch_bounds__(512) void gemm_out_pipe(
    const unsigned short* __restrict__ A, const unsigned short* __restrict__ W,
    float* __restrict__ C) {
  __shared__ __align__(16) char SM[131072];
  const int tid = threadIdx.x;
  const int lane = tid & 63, wv = tid >> 6;
  const int wr = wv >> 2, wc = wv & 3;
  const int g = lane >> 4, lr = lane & 15;
  const int m0 = blockIdx.y * 256, n0 = blockIdx.x * 256;

  PIPE256_SETUP(A, W)

  f32x4 acc[8][4];
#pragma unroll
  for (int i = 0; i < 8; ++i)
#pragma unroll
    for (int j = 0; j < 4; ++j) acc[i][j] = (f32x4){0.f, 0.f, 0.f, 0.f};

  PIPE256_PROLOGUE()
  PIPE256_LOOP()

#pragma unroll
  for (int mi = 0; mi < 8; ++mi)
#pragma unroll
    for (int ni = 0; ni < 4; ++ni)
#pragma unroll
      for (int r = 0; r < 4; ++r) {
        const int row = m0 + wr * 128 + mi * 16 + g * 4 + r;
        const int col = n0 + wc * 64 + ni * 16 + lr;
        C[(size_t)row * HIDDEN + col] = acc[mi][ni][r];
      }
}

// ---------------------------------------------------------------------------
// MFMA flash attention (unchanged from rounds 6-10: 256 thr / 4 waves,
// 3-deep ring, counted vmcnt(4) + raw s_barrier, per-lane deferred l-sum,
// setprio, head-aligned XCD grid). K blocked [S/32][d/8][s%32][8], V blocked
// [S/8][D][8]. Log2-domain softmax, defer-max THR=8.
// ---------------------------------------------------------------------------
__global__ __launch_bounds__(256, 3) void attn_mfma(const unsigned short* __restrict__ Q,
                                                    const unsigned short* __restrict__ K,
                                                    const unsigned short* __restrict__ V,
                                                    unsigned short* __restrict__ Ab) {
  const int bid = blockIdx.x;
  const int bh = bid & 31;            // bid%8 == bh%8 -> head-aligned XCD
  const int q0 = (bid >> 5) * 128;
  const int tid = threadIdx.x;
  const int wv = tid >> 6, lane = tid & 63;
  const int g = lane >> 4, lr = lane & 15;
  const unsigned short* Qh = Q + (size_t)bh * SEQ * DH;
  const unsigned short* Kh = K + (size_t)bh * SEQ * DH;
  const unsigned short* Vh = V + (size_t)bh * SEQ * DH;

  __shared__ __align__(16) unsigned short Kls[3][4096];
  __shared__ __align__(16) unsigned short Vls[3][4096];
  __shared__ __align__(16) unsigned short Pw[4][16][40];

  bf16x8 qf[2][4];
#pragma unroll
  for (int m = 0; m < 2; ++m)
#pragma unroll
    for (int kb = 0; kb < 4; ++kb)
      qf[m][kb] = *(const bf16x8*)&Qh[(size_t)(q0 + wv * 32 + m * 16 + lr) * DH +
                                      kb * 32 + g * 8];

  f32x4 acc[2][8];
#pragma unroll
  for (int m = 0; m < 2; ++m)
#pragma unroll
    for (int dn = 0; dn < 8; ++dn) acc[m][dn] = (f32x4){0.f, 0.f, 0.f, 0.f};
  float mrun[2] = {-1e30f, -1e30f};
  float lrun[2] = {0.f, 0.f};

  // prologue: stage tiles 0 and 1
#pragma unroll
  for (int tt = 0; tt < 2; ++tt)
#pragma unroll
    for (int j = 0; j < 2; ++j) {
      const int c = j * 256 + tid;
      gll16(Kh + (size_t)tt * 4096 + c * 8, (char*)&Kls[tt][0] + j * 4096 + wv * 1024);
      gll16(Vh + (size_t)tt * 4096 + c * 8, (char*)&Vls[tt][0] + j * 4096 + wv * 1024);
    }

  for (int t = 0; t < 64; ++t) {
    const int cur = t % 3;
    asm volatile("s_waitcnt vmcnt(4)" ::: "memory");
    __builtin_amdgcn_s_barrier();
    if (t + 2 < 64) {
      const int nx = (t + 2) % 3;
      const unsigned short* Kn = Kh + (size_t)(t + 2) * 4096;
      const unsigned short* Vn = Vh + (size_t)(t + 2) * 4096;
      char* kd = (char*)&Kls[nx][0];
      char* vd = (char*)&Vls[nx][0];
#pragma unroll
      for (int j = 0; j < 2; ++j) {
        const int c = j * 256 + tid;
        gll16(Kn + (size_t)c * 8, kd + j * 4096 + wv * 1024);
        gll16(Vn + (size_t)c * 8, vd + j * 4096 + wv * 1024);
      }
    }

    const char* Kc = (const char*)&Kls[cur][0];
    const char* Vc = (const char*)&Vls[cur][0];
    bf16x8 ap[2];
#pragma unroll
    for (int m = 0; m < 2; ++m) {
      f32x4 st0 = (f32x4){0.f, 0.f, 0.f, 0.f};
      f32x4 st1 = (f32x4){0.f, 0.f, 0.f, 0.f};
      __builtin_amdgcn_s_setprio(1);
#pragma unroll
      for (int kb = 0; kb < 4; ++kb) {
        const int cb = (kb * 4 + g) * 32;
        bf16x8 kf0 = *(const bf16x8*)(Kc + (cb + lr) * 16);
        bf16x8 kf1 = *(const bf16x8*)(Kc + (cb + 16 + lr) * 16);
        st0 = mfma16(kf0, qf[m][kb], st0);
        st1 = mfma16(kf1, qf[m][kb], st1);
      }
      __builtin_amdgcn_s_setprio(0);
      float mt = fmaxf(fmaxf(fmaxf(st0[0], st0[1]), fmaxf(st0[2], st0[3])),
                       fmaxf(fmaxf(st1[0], st1[1]), fmaxf(st1[2], st1[3])));
      mt = fmaxf(mt, __shfl_xor(mt, 16));
      mt = fmaxf(mt, __shfl_xor(mt, 32));
      if (!__all(mt <= mrun[m] + 8.0f)) {  // rare rescale (defer-max)
        const float mnew = fmaxf(mrun[m], mt);
        const float corr = __builtin_amdgcn_exp2f(mrun[m] - mnew);
        lrun[m] *= corr;
        mrun[m] = mnew;
        const f32x4 cv = (f32x4){__shfl(corr, g * 4 + 0), __shfl(corr, g * 4 + 1),
                                 __shfl(corr, g * 4 + 2), __shfl(corr, g * 4 + 3)};
#pragma unroll
        for (int dn = 0; dn < 8; ++dn) acc[m][dn] *= cv;
      }
      float p[8], ls = 0.f;
#pragma unroll
      for (int r = 0; r < 4; ++r) {
        p[r] = __builtin_amdgcn_exp2f(st0[r] - mrun[m]);
        p[4 + r] = __builtin_amdgcn_exp2f(st1[r] - mrun[m]);
        ls += p[r] + p[4 + r];
      }
      lrun[m] += ls;  // per-lane partial; cross-lane reduce deferred to end
      uint2 pk0, pk1;
      pk0.x = cvtpk(p[0], p[1]); pk0.y = cvtpk(p[2], p[3]);
      pk1.x = cvtpk(p[4], p[5]); pk1.y = cvtpk(p[6], p[7]);
      *(uint2*)&Pw[wv][lr][4 * g] = pk0;
      *(uint2*)&Pw[wv][lr][16 + 4 * g] = pk1;
      ap[m] = *(const bf16x8*)&Pw[wv][lr][8 * g];
    }
    // PV
    __builtin_amdgcn_s_setprio(1);
#pragma unroll
    for (int dn = 0; dn < 8; ++dn) {
      bf16x8 vf = *(const bf16x8*)(Vc + (g * 128 + dn * 16 + lr) * 16);
      acc[0][dn] = mfma16(ap[0], vf, acc[0][dn]);
      acc[1][dn] = mfma16(ap[1], vf, acc[1][dn]);
    }
    __builtin_amdgcn_s_setprio(0);
  }

  const int b = bh >> 4, h = bh & 15;
#pragma unroll
  for (int m = 0; m < 2; ++m) {
    lrun[m] += __shfl_xor(lrun[m], 16);
    lrun[m] += __shfl_xor(lrun[m], 32);
    const float inv = 1.f / lrun[m];
    float ir[4];
#pragma unroll
    for (int r = 0; r < 4; ++r) ir[r] = __shfl(inv, g * 4 + r);
#pragma unroll
    for (int dn = 0; dn < 8; ++dn)
#pragma unroll
      for (int r = 0; r < 4; ++r) {
        const int srow = q0 + wv * 32 + m * 16 + g * 4 + r;
        Ab[((size_t)(b * SEQ + srow) * NHEADS + h) * DH + dn * 16 + lr] =
            f2bf(acc[m][dn][r] * ir[r]);
      }
  }
}

// ---------------------------------------------------------------------------
extern "C" void kernel_launch(void* const* d_in, const int* in_sizes, int n_in,
                              void* d_out, int out_size, void* d_ws,
                              size_t ws_size, hipStream_t stream) {
  const float* X  = (const float*)d_in[0];
  const float* Wq = (const float*)d_in[1];
  const float* Wk = (const float*)d_in[2];
  const float* Wv = (const float*)d_in[3];
  const float* Wo = (const float*)d_in[4];
  float* out = (float*)d_out;

  const int n1 = MTOT * HIDDEN;    // 8388608
  const int n2 = HIDDEN * HIDDEN;  // 4194304

  char* p = (char*)d_ws;
  unsigned short* Xb  = (unsigned short*)(p + 0);          // 16 MB
  unsigned short* Qb  = (unsigned short*)(p + 16777216);   // 16 MB
  unsigned short* Kb  = (unsigned short*)(p + 33554432);   // 16 MB
  unsigned short* Vb  = (unsigned short*)(p + 50331648);   // 16 MB
  unsigned short* Wqb = (unsigned short*)(p + 67108864);   // 8 MB
  unsigned short* Wkb = (unsigned short*)(p + 75497472);   // 8 MB
  unsigned short* Wvb = (unsigned short*)(p + 83886080);   // 8 MB
  unsigned short* Wob = (unsigned short*)(p + 92274688);   // 8 MB
  unsigned short* Ab  = (unsigned short*)(p + 100663296);  // 16 MB (ends 117440512)

  cast_all<<<(n1 + 4 * n2) / 1024, 256, 0, stream>>>(X, Wq, Wk, Wv, Wo, Xb, Wqb,
                                                     Wkb, Wvb, Wob);

  gemm_qkv_pipe<<<dim3(24, 16), 512, 0, stream>>>(Xb, Wqb, Wkb, Wvb,
                                                  Qb, Kb, Vb);

  attn_mfma<<<dim3(512), 256, 0, stream>>>(Qb, Kb, Vb, Ab);

  gemm_out_pipe<<<dim3(8, 16), 512, 0, stream>>>(Ab, Wob, out);
}

// Round 12
// 301.403 us; speedup vs baseline: 1.0333x; 1.0333x over previous
//
#include <hip/hip_runtime.h>
#include <cstdint>

#define HIDDEN 2048
#define NHEADS 16
#define DH 128
#define BATCH 2
#define SEQ 2048
#define MTOT 4096
#define BH (BATCH * NHEADS)

typedef __attribute__((ext_vector_type(8))) short bf16x8;
typedef __attribute__((ext_vector_type(4))) float f32x4;

// SCALE * log2(e): scores come out of QK^T already in log2 domain
static constexpr float QSCALE = (float)(0.08838834764831845 * 1.4426950408889634);

__device__ __forceinline__ unsigned short f2bf(float f) {
  union { float f; uint32_t u; } v; v.f = f;
  uint32_t r = v.u + 0x7FFFu + ((v.u >> 16) & 1u);
  return (unsigned short)(r >> 16);
}
__device__ __forceinline__ uint32_t cvtpk(float lo, float hi) {
  uint32_t r;
  asm("v_cvt_pk_bf16_f32 %0, %1, %2" : "=v"(r) : "v"(lo), "v"(hi));
  return r;
}
__device__ __forceinline__ f32x4 mfma16(bf16x8 a, bf16x8 b, f32x4 c) {
  return __builtin_amdgcn_mfma_f32_16x16x32_bf16(a, b, c, 0, 0, 0);
}

typedef const __attribute__((address_space(1))) unsigned char* gas1_t;
typedef __attribute__((address_space(3))) unsigned char* las3_t;
__device__ __forceinline__ void gll16(const void* g, void* l) {
  __builtin_amdgcn_global_load_lds((gas1_t)g, (las3_t)l, 16, 0, 0);
}

// ---------------------------------------------------------------------------
// Fused cast: X (8.4M) + Wq/Wk/Wv/Wo (4.2M each), fp32 -> bf16, one launch.
// ---------------------------------------------------------------------------
__global__ __launch_bounds__(256) void cast_all(
    const float* __restrict__ X, const float* __restrict__ Wq,
    const float* __restrict__ Wk, const float* __restrict__ Wv,
    const float* __restrict__ Wo, unsigned short* __restrict__ Xb,
    unsigned short* __restrict__ Wqb, unsigned short* __restrict__ Wkb,
    unsigned short* __restrict__ Wvb, unsigned short* __restrict__ Wob) {
  const int n1 = MTOT * HIDDEN;           // 8388608
  const int i = (blockIdx.x * 256 + threadIdx.x) * 4;
  const float* s;
  unsigned short* d;
  int o;
  if (i < n1) {
    s = X; d = Xb; o = i;
  } else {
    const int j = i - n1;
    const int w = j >> 22;                 // n2 = 2^22
    o = j & ((1 << 22) - 1);
    s = (w == 0) ? Wq : (w == 1) ? Wk : (w == 2) ? Wv : Wo;
    d = (w == 0) ? Wqb : (w == 1) ? Wkb : (w == 2) ? Wvb : Wob;
  }
  float4 f = *(const float4*)&s[o];
  ushort4 u;
  u.x = f2bf(f.x); u.y = f2bf(f.y); u.z = f2bf(f.z); u.w = f2bf(f.w);
  *(ushort4*)&d[o] = u;
}

// ---------------------------------------------------------------------------
// 256x256 8-phase GEMM template (m201-style). BK=64, 512 thr / 8 waves
// (2M x 4N), per-wave 128x64 output: acc[8][4] f32x4. LDS: 2 buffers x 64KB,
// k-half-major: A @ {ks*16384 + row*64 + (j ^ ((row>>1)&3))*16}, B @ +32768.
// SWIZZLE f(row) = (row>>1)&3  (r11 used row&3 -> 4-way conflict, 9.4M
// SQ_LDS_BANK_CONFLICT; (row>>1)&3 gives exactly 8 words/bank = uniform).
// Per K-tile t (buffer t&1), 4 phases = (ks, mh), each:
//   {4-8 ds_read_b128 -> 2 gll16 (one 16KB half-stage) -> s_barrier ->
//    setprio(1) 16 MFMA setprio(0) -> s_barrier}
// B-frags held in regs across the two mh-phases of a ks.
// Rolling stage: ph1: A-k1(t+1)->other buf; ph2: B-k1(t+1)->other buf;
// ph3: A-k0(t+2)->this buf (k0 region retired at ph2 barrier);
// ph4: B-k0(t+2)->this buf. vmcnt(4) once per tile at end of ph4; pipe never
// drains until the 2-tile tail (vmcnt(0) at t=30, none at 31).
// Staging chunk c: row=c>>2, j=(c&3)^((row>>1)&3) -> inverse-permuted global
// source, linear LDS dest (rule #21).
// ---------------------------------------------------------------------------
template <int VM, bool PF1, bool PF2>
__device__ __forceinline__ void tile_body(
    int t, char* SM, const unsigned short* pa, const unsigned short* pb,
    int wv, int wr, int wc, int g, int lr, f32x4 (&acc)[8][4]) {
  char* buf  = SM + (size_t)((t & 1) * 65536);
  char* obuf = SM + (size_t)(((t + 1) & 1) * 65536);
  const int swz16 = (g ^ ((lr >> 1) & 3)) * 16;
  const size_t ko1 = (size_t)(t + 1) * 64 + 32;  // k1 of tile t+1
  const size_t ko0 = (size_t)(t + 2) * 64;       // k0 of tile t+2
  const size_t rowskip = (size_t)128 * HIDDEN;
  bf16x8 a[4], b[4];

  // ---- phase 1: ks=0, mh=0 (loads B ks0) ----
#pragma unroll
  for (int mi = 0; mi < 4; ++mi)
    a[mi] = *(const bf16x8*)(buf + (wr * 128 + mi * 16 + lr) * 64 + swz16);
#pragma unroll
  for (int ni = 0; ni < 4; ++ni)
    b[ni] = *(const bf16x8*)(buf + 32768 + (wc * 64 + ni * 16 + lr) * 64 + swz16);
  if (PF1) {
    char* d = obuf + 16384 + wv * 1024;
    gll16(pa + ko1, d);
    gll16(pa + rowskip + ko1, d + 8192);
  }
  __builtin_amdgcn_s_barrier();
  __builtin_amdgcn_s_setprio(1);
#pragma unroll
  for (int mi = 0; mi < 4; ++mi)
#pragma unroll
    for (int ni = 0; ni < 4; ++ni)
      acc[mi][ni] = mfma16(a[mi], b[ni], acc[mi][ni]);
  __builtin_amdgcn_s_setprio(0);
  __builtin_amdgcn_s_barrier();

  // ---- phase 2: ks=0, mh=1 (B held) ----
#pragma unroll
  for (int mi = 0; mi < 4; ++mi)
    a[mi] = *(const bf16x8*)(buf + (wr * 128 + 64 + mi * 16 + lr) * 64 + swz16);
  if (PF1) {
    char* d = obuf + 32768 + 16384 + wv * 1024;
    gll16(pb + ko1, d);
    gll16(pb + rowskip + ko1, d + 8192);
  }
  __builtin_amdgcn_s_barrier();
  __builtin_amdgcn_s_setprio(1);
#pragma unroll
  for (int mi = 0; mi < 4; ++mi)
#pragma unroll
    for (int ni = 0; ni < 4; ++ni)
      acc[4 + mi][ni] = mfma16(a[mi], b[ni], acc[4 + mi][ni]);
  __builtin_amdgcn_s_setprio(0);
  __builtin_amdgcn_s_barrier();

  // ---- phase 3: ks=1, mh=0 (loads B ks1) ----
#pragma unroll
  for (int mi = 0; mi < 4; ++mi)
    a[mi] = *(const bf16x8*)(buf + 16384 + (wr * 128 + mi * 16 + lr) * 64 + swz16);
#pragma unroll
  for (int ni = 0; ni < 4; ++ni)
    b[ni] = *(const bf16x8*)(buf + 32768 + 16384 + (wc * 64 + ni * 16 + lr) * 64 + swz16);
  if (PF2) {
    char* d = buf + wv * 1024;  // k0 region of THIS buf: retired at ph2 barrier
    gll16(pa + ko0, d);
    gll16(pa + rowskip + ko0, d + 8192);
  }
  __builtin_amdgcn_s_barrier();
  __builtin_amdgcn_s_setprio(1);
#pragma unroll
  for (int mi = 0; mi < 4; ++mi)
#pragma unroll
    for (int ni = 0; ni < 4; ++ni)
      acc[mi][ni] = mfma16(a[mi], b[ni], acc[mi][ni]);
  __builtin_amdgcn_s_setprio(0);
  __builtin_amdgcn_s_barrier();

  // ---- phase 4: ks=1, mh=1; vmcnt once per K-tile ----
#pragma unroll
  for (int mi = 0; mi < 4; ++mi)
    a[mi] = *(const bf16x8*)(buf + 16384 + (wr * 128 + 64 + mi * 16 + lr) * 64 + swz16);
  if (PF2) {
    char* d = buf + 32768 + wv * 1024;
    gll16(pb + ko0, d);
    gll16(pb + rowskip + ko0, d + 8192);
  }
  __builtin_amdgcn_s_barrier();
  __builtin_amdgcn_s_setprio(1);
#pragma unroll
  for (int mi = 0; mi < 4; ++mi)
#pragma unroll
    for (int ni = 0; ni < 4; ++ni)
      acc[4 + mi][ni] = mfma16(a[mi], b[ni], acc[4 + mi][ni]);
  __builtin_amdgcn_s_setprio(0);
  if (VM == 4) asm volatile("s_waitcnt vmcnt(4)" ::: "memory");
  else if (VM == 0) asm volatile("s_waitcnt vmcnt(0)" ::: "memory");
  if (VM >= 0) __builtin_amdgcn_s_barrier();
}

#define PIPE256_SETUP(Abase, Bbase)                                           \
  const int c0 = wv * 64 + lane;                                              \
  const int row0 = c0 >> 2, j0 = (c0 & 3) ^ ((row0 >> 1) & 3);                \
  const unsigned short* pa = (Abase) + (size_t)(m0 + row0) * HIDDEN + j0 * 8; \
  const unsigned short* pb = (Bbase) + (size_t)(n0 + row0) * HIDDEN + j0 * 8; \
  const size_t rsk = (size_t)128 * HIDDEN;

#define PIPE256_PROLOGUE()                                                    \
  {                                                                           \
    char* dA0 = SM + wv * 1024;                                               \
    gll16(pa + 0, dA0); gll16(pa + rsk + 0, dA0 + 8192);                      \
    char* dB0 = SM + 32768 + wv * 1024;                                       \
    gll16(pb + 0, dB0); gll16(pb + rsk + 0, dB0 + 8192);                      \
    char* dA1 = SM + 16384 + wv * 1024;                                       \
    gll16(pa + 32, dA1); gll16(pa + rsk + 32, dA1 + 8192);                    \
    char* dB1 = SM + 32768 + 16384 + wv * 1024;                               \
    gll16(pb + 32, dB1); gll16(pb + rsk + 32, dB1 + 8192);                    \
    char* eA0 = SM + 65536 + wv * 1024;                                       \
    gll16(pa + 64, eA0); gll16(pa + rsk + 64, eA0 + 8192);                    \
    char* eB0 = SM + 65536 + 32768 + wv * 1024;                               \
    gll16(pb + 64, eB0); gll16(pb + rsk + 64, eB0 + 8192);                    \
  }                                                                           \
  asm volatile("s_waitcnt vmcnt(4)" ::: "memory");                            \
  __builtin_amdgcn_s_barrier();

#define PIPE256_LOOP()                                                        \
  for (int t = 0; t < 30; ++t)                                                \
    tile_body<4, true, true>(t, SM, pa, pb, wv, wr, wc, g, lr, acc);          \
  tile_body<0, true, false>(30, SM, pa, pb, wv, wr, wc, g, lr, acc);          \
  tile_body<-1, false, false>(31, SM, pa, pb, wv, wr, wc, g, lr, acc);

// ---------------------------------------------------------------------------
// Fused Q/K/V projection, 256x256 tiles. grid (24, 16): which = x>>3,
// n0 = (x&7)*256 (x%8 pins n-panel to an XCD), m0 = y*256.
// which 0: Q [BH][S][D] (alpha=QSCALE); 1: K blocked [BH][S/32][d/8][s%32][8];
// 2: V blocked [BH][S/8][D][8].
// ---------------------------------------------------------------------------
__global__ __launch_bounds__(512) void gemm_qkv_pipe(
    const unsigned short* __restrict__ A, const unsigned short* __restrict__ Wq,
    const unsigned short* __restrict__ Wk, const unsigned short* __restrict__ Wv,
    unsigned short* __restrict__ Qb, unsigned short* __restrict__ Kb,
    unsigned short* __restrict__ Vb) {
  __shared__ __align__(16) char SM[131072];
  const int tid = threadIdx.x;
  const int lane = tid & 63, wv = tid >> 6;
  const int wr = wv >> 2, wc = wv & 3;
  const int g = lane >> 4, lr = lane & 15;
  const int which = blockIdx.x >> 3;
  const int m0 = blockIdx.y * 256, n0 = (blockIdx.x & 7) * 256;
  const unsigned short* W = (which == 0) ? Wq : (which == 1) ? Wk : Wv;

  PIPE256_SETUP(A, W)

  f32x4 acc[8][4];
#pragma unroll
  for (int i = 0; i < 8; ++i)
#pragma unroll
    for (int j = 0; j < 4; ++j) acc[i][j] = (f32x4){0.f, 0.f, 0.f, 0.f};

  PIPE256_PROLOGUE()
  PIPE256_LOOP()

  const float alpha = (which == 0) ? QSCALE : 1.0f;
  unsigned short* C = (which == 0) ? Qb : (which == 1) ? Kb : Vb;
#pragma unroll
  for (int mi = 0; mi < 8; ++mi)
#pragma unroll
    for (int ni = 0; ni < 4; ++ni)
#pragma unroll
      for (int r = 0; r < 4; ++r) {
        const int row = m0 + wr * 128 + mi * 16 + g * 4 + r;
        const int col = n0 + wc * 64 + ni * 16 + lr;
        const unsigned short v = f2bf(acc[mi][ni][r] * alpha);
        const int b = row >> 11, s = row & (SEQ - 1);
        const int h = col >> 7, d = col & (DH - 1);
        const size_t base = (size_t)(b * NHEADS + h) * SEQ * DH;
        if (which == 0)
          C[base + (size_t)s * DH + d] = v;
        else if (which == 1)
          C[base + (size_t)(s >> 5) * 4096 + (d >> 3) * 256 + (s & 31) * 8 + (d & 7)] = v;
        else
          C[base + (size_t)(s >> 3) * 1024 + d * 8 + (s & 7)] = v;
      }
}

// ---------------------------------------------------------------------------
// O-projection, 256x256 tiles: C(f32)[4096][2048] = A_bf16 @ Wo_bf16^T.
// grid (8, 16) = 128 blocks.
// ---------------------------------------------------------------------------
__global__ __launch_bounds__(512) void gemm_out_pipe(
    const unsigned short* __restrict__ A, const unsigned short* __restrict__ W,
    float* __restrict__ C) {
  __shared__ __align__(16) char SM[131072];
  const int tid = threadIdx.x;
  const int lane = tid & 63, wv = tid >> 6;
  const int wr = wv >> 2, wc = wv & 3;
  const int g = lane >> 4, lr = lane & 15;
  const int m0 = blockIdx.y * 256, n0 = blockIdx.x * 256;

  PIPE256_SETUP(A, W)

  f32x4 acc[8][4];
#pragma unroll
  for (int i = 0; i < 8; ++i)
#pragma unroll
    for (int j = 0; j < 4; ++j) acc[i][j] = (f32x4){0.f, 0.f, 0.f, 0.f};

  PIPE256_PROLOGUE()
  PIPE256_LOOP()

#pragma unroll
  for (int mi = 0; mi < 8; ++mi)
#pragma unroll
    for (int ni = 0; ni < 4; ++ni)
#pragma unroll
      for (int r = 0; r < 4; ++r) {
        const int row = m0 + wr * 128 + mi * 16 + g * 4 + r;
        const int col = n0 + wc * 64 + ni * 16 + lr;
        C[(size_t)row * HIDDEN + col] = acc[mi][ni][r];
      }
}

// ---------------------------------------------------------------------------
// MFMA flash attention (unchanged from rounds 6-11: 256 thr / 4 waves,
// 3-deep ring, counted vmcnt(4) + raw s_barrier, per-lane deferred l-sum,
// setprio, head-aligned XCD grid). K blocked [S/32][d/8][s%32][8], V blocked
// [S/8][D][8]. Log2-domain softmax, defer-max THR=8.
// ---------------------------------------------------------------------------
__global__ __launch_bounds__(256, 3) void attn_mfma(const unsigned short* __restrict__ Q,
                                                    const unsigned short* __restrict__ K,
                                                    const unsigned short* __restrict__ V,
                                                    unsigned short* __restrict__ Ab) {
  const int bid = blockIdx.x;
  const int bh = bid & 31;            // bid%8 == bh%8 -> head-aligned XCD
  const int q0 = (bid >> 5) * 128;
  const int tid = threadIdx.x;
  const int wv = tid >> 6, lane = tid & 63;
  const int g = lane >> 4, lr = lane & 15;
  const unsigned short* Qh = Q + (size_t)bh * SEQ * DH;
  const unsigned short* Kh = K + (size_t)bh * SEQ * DH;
  const unsigned short* Vh = V + (size_t)bh * SEQ * DH;

  __shared__ __align__(16) unsigned short Kls[3][4096];
  __shared__ __align__(16) unsigned short Vls[3][4096];
  __shared__ __align__(16) unsigned short Pw[4][16][40];

  bf16x8 qf[2][4];
#pragma unroll
  for (int m = 0; m < 2; ++m)
#pragma unroll
    for (int kb = 0; kb < 4; ++kb)
      qf[m][kb] = *(const bf16x8*)&Qh[(size_t)(q0 + wv * 32 + m * 16 + lr) * DH +
                                      kb * 32 + g * 8];

  f32x4 acc[2][8];
#pragma unroll
  for (int m = 0; m < 2; ++m)
#pragma unroll
    for (int dn = 0; dn < 8; ++dn) acc[m][dn] = (f32x4){0.f, 0.f, 0.f, 0.f};
  float mrun[2] = {-1e30f, -1e30f};
  float lrun[2] = {0.f, 0.f};

  // prologue: stage tiles 0 and 1
#pragma unroll
  for (int tt = 0; tt < 2; ++tt)
#pragma unroll
    for (int j = 0; j < 2; ++j) {
      const int c = j * 256 + tid;
      gll16(Kh + (size_t)tt * 4096 + c * 8, (char*)&Kls[tt][0] + j * 4096 + wv * 1024);
      gll16(Vh + (size_t)tt * 4096 + c * 8, (char*)&Vls[tt][0] + j * 4096 + wv * 1024);
    }

  for (int t = 0; t < 64; ++t) {
    const int cur = t % 3;
    asm volatile("s_waitcnt vmcnt(4)" ::: "memory");
    __builtin_amdgcn_s_barrier();
    if (t + 2 < 64) {
      const int nx = (t + 2) % 3;
      const unsigned short* Kn = Kh + (size_t)(t + 2) * 4096;
      const unsigned short* Vn = Vh + (size_t)(t + 2) * 4096;
      char* kd = (char*)&Kls[nx][0];
      char* vd = (char*)&Vls[nx][0];
#pragma unroll
      for (int j = 0; j < 2; ++j) {
        const int c = j * 256 + tid;
        gll16(Kn + (size_t)c * 8, kd + j * 4096 + wv * 1024);
        gll16(Vn + (size_t)c * 8, vd + j * 4096 + wv * 1024);
      }
    }

    const char* Kc = (const char*)&Kls[cur][0];
    const char* Vc = (const char*)&Vls[cur][0];
    bf16x8 ap[2];
#pragma unroll
    for (int m = 0; m < 2; ++m) {
      f32x4 st0 = (f32x4){0.f, 0.f, 0.f, 0.f};
      f32x4 st1 = (f32x4){0.f, 0.f, 0.f, 0.f};
      __builtin_amdgcn_s_setprio(1);
#pragma unroll
      for (int kb = 0; kb < 4; ++kb) {
        const int cb = (kb * 4 + g) * 32;
        bf16x8 kf0 = *(const bf16x8*)(Kc + (cb + lr) * 16);
        bf16x8 kf1 = *(const bf16x8*)(Kc + (cb + 16 + lr) * 16);
        st0 = mfma16(kf0, qf[m][kb], st0);
        st1 = mfma16(kf1, qf[m][kb], st1);
      }
      __builtin_amdgcn_s_setprio(0);
      float mt = fmaxf(fmaxf(fmaxf(st0[0], st0[1]), fmaxf(st0[2], st0[3])),
                       fmaxf(fmaxf(st1[0], st1[1]), fmaxf(st1[2], st1[3])));
      mt = fmaxf(mt, __shfl_xor(mt, 16));
      mt = fmaxf(mt, __shfl_xor(mt, 32));
      if (!__all(mt <= mrun[m] + 8.0f)) {  // rare rescale (defer-max)
        const float mnew = fmaxf(mrun[m], mt);
        const float corr = __builtin_amdgcn_exp2f(mrun[m] - mnew);
        lrun[m] *= corr;
        mrun[m] = mnew;
        const f32x4 cv = (f32x4){__shfl(corr, g * 4 + 0), __shfl(corr, g * 4 + 1),
                                 __shfl(corr, g * 4 + 2), __shfl(corr, g * 4 + 3)};
#pragma unroll
        for (int dn = 0; dn < 8; ++dn) acc[m][dn] *= cv;
      }
      float p[8], ls = 0.f;
#pragma unroll
      for (int r = 0; r < 4; ++r) {
        p[r] = __builtin_amdgcn_exp2f(st0[r] - mrun[m]);
        p[4 + r] = __builtin_amdgcn_exp2f(st1[r] - mrun[m]);
        ls += p[r] + p[4 + r];
      }
      lrun[m] += ls;  // per-lane partial; cross-lane reduce deferred to end
      uint2 pk0, pk1;
      pk0.x = cvtpk(p[0], p[1]); pk0.y = cvtpk(p[2], p[3]);
      pk1.x = cvtpk(p[4], p[5]); pk1.y = cvtpk(p[6], p[7]);
      *(uint2*)&Pw[wv][lr][4 * g] = pk0;
      *(uint2*)&Pw[wv][lr][16 + 4 * g] = pk1;
      ap[m] = *(const bf16x8*)&Pw[wv][lr][8 * g];
    }
    // PV
    __builtin_amdgcn_s_setprio(1);
#pragma unroll
    for (int dn = 0; dn < 8; ++dn) {
      bf16x8 vf = *(const bf16x8*)(Vc + (g * 128 + dn * 16 + lr) * 16);
      acc[0][dn] = mfma16(ap[0], vf, acc[0][dn]);
      acc[1][dn] = mfma16(ap[1], vf, acc[1][dn]);
    }
    __builtin_amdgcn_s_setprio(0);
  }

  const int b = bh >> 4, h = bh & 15;
#pragma unroll
  for (int m = 0; m < 2; ++m) {
    lrun[m] += __shfl_xor(lrun[m], 16);
    lrun[m] += __shfl_xor(lrun[m], 32);
    const float inv = 1.f / lrun[m];
    float ir[4];
#pragma unroll
    for (int r = 0; r < 4; ++r) ir[r] = __shfl(inv, g * 4 + r);
#pragma unroll
    for (int dn = 0; dn < 8; ++dn)
#pragma unroll
      for (int r = 0; r < 4; ++r) {
        const int srow = q0 + wv * 32 + m * 16 + g * 4 + r;
        Ab[((size_t)(b * SEQ + srow) * NHEADS + h) * DH + dn * 16 + lr] =
            f2bf(acc[m][dn][r] * ir[r]);
      }
  }
}

// ---------------------------------------------------------------------------
extern "C" void kernel_launch(void* const* d_in, const int* in_sizes, int n_in,
                              void* d_out, int out_size, void* d_ws,
                              size_t ws_size, hipStream_t stream) {
  const float* X  = (const float*)d_in[0];
  const float* Wq = (const float*)d_in[1];
  const float* Wk = (const float*)d_in[2];
  const float* Wv = (const float*)d_in[3];
  const float* Wo = (const float*)d_in[4];
  float* out = (float*)d_out;

  const int n1 = MTOT * HIDDEN;    // 8388608
  const int n2 = HIDDEN * HIDDEN;  // 4194304

  char* p = (char*)d_ws;
  unsigned short* Xb  = (unsigned short*)(p + 0);          // 16 MB
  unsigned short* Qb  = (unsigned short*)(p + 16777216);   // 16 MB
  unsigned short* Kb  = (unsigned short*)(p + 33554432);   // 16 MB
  unsigned short* Vb  = (unsigned short*)(p + 50331648);   // 16 MB
  unsigned short* Wqb = (unsigned short*)(p + 67108864);   // 8 MB
  unsigned short* Wkb = (unsigned short*)(p + 75497472);   // 8 MB
  unsigned short* Wvb = (unsigned short*)(p + 83886080);   // 8 MB
  unsigned short* Wob = (unsigned short*)(p + 92274688);   // 8 MB
  unsigned short* Ab  = (unsigned short*)(p + 100663296);  // 16 MB (ends 117440512)

  cast_all<<<(n1 + 4 * n2) / 1024, 256, 0, stream>>>(X, Wq, Wk, Wv, Wo, Xb, Wqb,
                                                     Wkb, Wvb, Wob);

  gemm_qkv_pipe<<<dim3(24, 16), 512, 0, stream>>>(Xb, Wqb, Wkb, Wvb,
                                                  Qb, Kb, Vb);

  attn_mfma<<<dim3(512), 256, 0, stream>>>(Qb, Kb, Vb, Ab);

  gemm_out_pipe<<<dim3(8, 16), 512, 0, stream>>>(Ab, Wob, out);
}

// Round 13
// 269.427 us; speedup vs baseline: 1.1559x; 1.1187x over previous
//
#include <hip/hip_runtime.h>
#include <cstdint>

#define HIDDEN 2048
#define NHEADS 16
#define DH 128
#define BATCH 2
#define SEQ 2048
#define MTOT 4096
#define BH (BATCH * NHEADS)

typedef __attribute__((ext_vector_type(8))) short bf16x8;
typedef __attribute__((ext_vector_type(4))) float f32x4;

// SCALE * log2(e): scores come out of QK^T already in log2 domain
static constexpr float QSCALE = (float)(0.08838834764831845 * 1.4426950408889634);

__device__ __forceinline__ unsigned short f2bf(float f) {
  union { float f; uint32_t u; } v; v.f = f;
  uint32_t r = v.u + 0x7FFFu + ((v.u >> 16) & 1u);
  return (unsigned short)(r >> 16);
}
__device__ __forceinline__ uint32_t cvtpk(float lo, float hi) {
  uint32_t r;
  asm("v_cvt_pk_bf16_f32 %0, %1, %2" : "=v"(r) : "v"(lo), "v"(hi));
  return r;
}
__device__ __forceinline__ f32x4 mfma16(bf16x8 a, bf16x8 b, f32x4 c) {
  return __builtin_amdgcn_mfma_f32_16x16x32_bf16(a, b, c, 0, 0, 0);
}

typedef const __attribute__((address_space(1))) unsigned char* gas1_t;
typedef __attribute__((address_space(3))) unsigned char* las3_t;
__device__ __forceinline__ void gll16(const void* g, void* l) {
  __builtin_amdgcn_global_load_lds((gas1_t)g, (las3_t)l, 16, 0, 0);
}

// ---------------------------------------------------------------------------
// Fused cast: X (8.4M) + Wq/Wk/Wv/Wo (4.2M each), fp32 -> bf16, one launch.
// ---------------------------------------------------------------------------
__global__ __launch_bounds__(256) void cast_all(
    const float* __restrict__ X, const float* __restrict__ Wq,
    const float* __restrict__ Wk, const float* __restrict__ Wv,
    const float* __restrict__ Wo, unsigned short* __restrict__ Xb,
    unsigned short* __restrict__ Wqb, unsigned short* __restrict__ Wkb,
    unsigned short* __restrict__ Wvb, unsigned short* __restrict__ Wob) {
  const int n1 = MTOT * HIDDEN;           // 8388608
  const int i = (blockIdx.x * 256 + threadIdx.x) * 4;
  const float* s;
  unsigned short* d;
  int o;
  if (i < n1) {
    s = X; d = Xb; o = i;
  } else {
    const int j = i - n1;
    const int w = j >> 22;                 // n2 = 2^22
    o = j & ((1 << 22) - 1);
    s = (w == 0) ? Wq : (w == 1) ? Wk : (w == 2) ? Wv : Wo;
    d = (w == 0) ? Wqb : (w == 1) ? Wkb : (w == 2) ? Wvb : Wob;
  }
  float4 f = *(const float4*)&s[o];
  ushort4 u;
  u.x = f2bf(f.x); u.y = f2bf(f.y); u.z = f2bf(f.z); u.w = f2bf(f.w);
  *(ushort4*)&d[o] = u;
}

// ---------------------------------------------------------------------------
// Single-barrier deep-pipelined GEMM body (r9, best measured). BM=128,
// BN=256, BK=64, 512 thr / 8 waves (2M x 4N), per-wave 64x64. 3-slot LDS
// ring (49152 B/slot: A 16KB @0, B 32KB @16384), prefetch tile kt+2. One
// barrier per K-tile, no read/MFMA phase separation: 8 phase-A ds_reads +
// 6 gll16 + 8 phase-B ds_reads, then two 16-MFMA clusters; compiler's
// dependency-driven lgkmcnt gates each cluster on its own reads. vmcnt(6)
// before the barrier keeps 2 staged tiles in flight.
// ---------------------------------------------------------------------------
template <int VM, bool PF>
__device__ __forceinline__ void pipe_body(
    int kt, char* SM, const unsigned short* aS0, const unsigned short* aS1,
    const unsigned short* bS0, const unsigned short* bS1,
    const unsigned short* bS2, const unsigned short* bS3, int wv, int wr,
    int wc, int g, int lr, f32x4 (&acc)[4][4]) {
  const char* Ac = SM + (kt % 3) * 49152;
  const char* Bc = Ac + 16384;
  char* slot2 = SM + ((kt + 2) % 3) * 49152;
  const size_t ko = (size_t)(kt + 2) * 64;
  const int rx = lr & 7;
  bf16x8 a0[4], b0[4], a1[4], b1[4];
#pragma unroll
  for (int mi = 0; mi < 4; ++mi)
    a0[mi] = *(const bf16x8*)(Ac + (wr * 64 + mi * 16 + lr) * 128 + ((g ^ rx) * 16));
#pragma unroll
  for (int ni = 0; ni < 4; ++ni)
    b0[ni] = *(const bf16x8*)(Bc + (wc * 64 + ni * 16 + lr) * 128 + ((g ^ rx) * 16));
  if (PF) {
    gll16(aS0 + ko, slot2 + wv * 2048);
    gll16(aS1 + ko, slot2 + wv * 2048 + 1024);
    gll16(bS0 + ko, slot2 + 16384 + wv * 4096);
    gll16(bS1 + ko, slot2 + 16384 + wv * 4096 + 1024);
    gll16(bS2 + ko, slot2 + 16384 + wv * 4096 + 2048);
    gll16(bS3 + ko, slot2 + 16384 + wv * 4096 + 3072);
  }
#pragma unroll
  for (int mi = 0; mi < 4; ++mi)
    a1[mi] = *(const bf16x8*)(Ac + (wr * 64 + mi * 16 + lr) * 128 + (((4 + g) ^ rx) * 16));
#pragma unroll
  for (int ni = 0; ni < 4; ++ni)
    b1[ni] = *(const bf16x8*)(Bc + (wc * 64 + ni * 16 + lr) * 128 + (((4 + g) ^ rx) * 16));
  __builtin_amdgcn_s_setprio(1);
#pragma unroll
  for (int mi = 0; mi < 4; ++mi)
#pragma unroll
    for (int ni = 0; ni < 4; ++ni)
      acc[mi][ni] = mfma16(a0[mi], b0[ni], acc[mi][ni]);
#pragma unroll
  for (int mi = 0; mi < 4; ++mi)
#pragma unroll
    for (int ni = 0; ni < 4; ++ni)
      acc[mi][ni] = mfma16(a1[mi], b1[ni], acc[mi][ni]);
  __builtin_amdgcn_s_setprio(0);
  if (VM == 6) asm volatile("s_waitcnt vmcnt(6)" ::: "memory");
  else if (VM == 0) asm volatile("s_waitcnt vmcnt(0)" ::: "memory");
  if (VM >= 0) __builtin_amdgcn_s_barrier();
}

// Per-thread staging source pointers (inverse of the LDS chunk permutation).
#define PIPE_SETUP(Abase, Bbase)                                              \
  const int idxA0 = wv * 128 + lane, idxA1 = idxA0 + 64;                      \
  const int rA0 = idxA0 >> 3, cA0 = (idxA0 & 7) ^ (rA0 & 7);                  \
  const int rA1 = idxA1 >> 3, cA1 = (idxA1 & 7) ^ (rA1 & 7);                  \
  const unsigned short* aS0 = (Abase) + (size_t)(m0 + rA0) * HIDDEN + cA0 * 8;\
  const unsigned short* aS1 = (Abase) + (size_t)(m0 + rA1) * HIDDEN + cA1 * 8;\
  const int idxB0 = wv * 256 + lane, idxB1 = idxB0 + 64,                      \
            idxB2 = idxB0 + 128, idxB3 = idxB0 + 192;                         \
  const int rB0 = idxB0 >> 3, cB0 = (idxB0 & 7) ^ (rB0 & 7);                  \
  const int rB1 = idxB1 >> 3, cB1 = (idxB1 & 7) ^ (rB1 & 7);                  \
  const int rB2 = idxB2 >> 3, cB2 = (idxB2 & 7) ^ (rB2 & 7);                  \
  const int rB3 = idxB3 >> 3, cB3 = (idxB3 & 7) ^ (rB3 & 7);                  \
  const unsigned short* bS0 = (Bbase) + (size_t)(n0 + rB0) * HIDDEN + cB0 * 8;\
  const unsigned short* bS1 = (Bbase) + (size_t)(n0 + rB1) * HIDDEN + cB1 * 8;\
  const unsigned short* bS2 = (Bbase) + (size_t)(n0 + rB2) * HIDDEN + cB2 * 8;\
  const unsigned short* bS3 = (Bbase) + (size_t)(n0 + rB3) * HIDDEN + cB3 * 8;

#define PIPE_PROLOGUE()                                                       \
  _Pragma("unroll") for (int tt = 0; tt < 2; ++tt) {                          \
    char* slot = SM + tt * 49152;                                             \
    const size_t ko = (size_t)tt * 64;                                        \
    gll16(aS0 + ko, slot + wv * 2048);                                        \
    gll16(aS1 + ko, slot + wv * 2048 + 1024);                                 \
    gll16(bS0 + ko, slot + 16384 + wv * 4096);                                \
    gll16(bS1 + ko, slot + 16384 + wv * 4096 + 1024);                         \
    gll16(bS2 + ko, slot + 16384 + wv * 4096 + 2048);                         \
    gll16(bS3 + ko, slot + 16384 + wv * 4096 + 3072);                         \
  }                                                                           \
  asm volatile("s_waitcnt vmcnt(6)" ::: "memory");                            \
  __builtin_amdgcn_s_barrier();

#define PIPE_LOOP()                                                           \
  for (int kt = 0; kt < 30; ++kt)                                             \
    pipe_body<6, true>(kt, SM, aS0, aS1, bS0, bS1, bS2, bS3, wv, wr, wc, g,   \
                       lr, acc);                                              \
  pipe_body<0, false>(30, SM, aS0, aS1, bS0, bS1, bS2, bS3, wv, wr, wc, g,    \
                      lr, acc);                                               \
  pipe_body<-1, false>(31, SM, aS0, aS1, bS0, bS1, bS2, bS3, wv, wr, wc, g,   \
                       lr, acc);

// ---------------------------------------------------------------------------
// Fused Q/K/V projection. grid (24, 32): which = x>>3, n0 = (x&7)*256.
// which 0: Q [BH][S][D] (alpha=QSCALE); 1: K blocked [BH][S/32][d/8][s%32][8];
// 2: V blocked [BH][S/8][D][8].
// ---------------------------------------------------------------------------
__global__ __launch_bounds__(512) void gemm_qkv_pipe(
    const unsigned short* __restrict__ A, const unsigned short* __restrict__ Wq,
    const unsigned short* __restrict__ Wk, const unsigned short* __restrict__ Wv,
    unsigned short* __restrict__ Qb, unsigned short* __restrict__ Kb,
    unsigned short* __restrict__ Vb) {
  __shared__ __align__(16) char SM[147456];
  const int tid = threadIdx.x;
  const int lane = tid & 63, wv = tid >> 6;
  const int wr = wv >> 2, wc = wv & 3;
  const int g = lane >> 4, lr = lane & 15;
  const int which = blockIdx.x >> 3;
  const int m0 = blockIdx.y * 128, n0 = (blockIdx.x & 7) * 256;
  const unsigned short* W = (which == 0) ? Wq : (which == 1) ? Wk : Wv;

  PIPE_SETUP(A, W)

  f32x4 acc[4][4];
#pragma unroll
  for (int i = 0; i < 4; ++i)
#pragma unroll
    for (int j = 0; j < 4; ++j) acc[i][j] = (f32x4){0.f, 0.f, 0.f, 0.f};

  PIPE_PROLOGUE()
  PIPE_LOOP()

  const float alpha = (which == 0) ? QSCALE : 1.0f;
  unsigned short* C = (which == 0) ? Qb : (which == 1) ? Kb : Vb;
#pragma unroll
  for (int mi = 0; mi < 4; ++mi)
#pragma unroll
    for (int ni = 0; ni < 4; ++ni)
#pragma unroll
      for (int r = 0; r < 4; ++r) {
        const int row = m0 + wr * 64 + mi * 16 + g * 4 + r;
        const int col = n0 + wc * 64 + ni * 16 + lr;
        const unsigned short v = f2bf(acc[mi][ni][r] * alpha);
        const int b = row >> 11, s = row & (SEQ - 1);
        const int h = col >> 7, d = col & (DH - 1);
        const size_t base = (size_t)(b * NHEADS + h) * SEQ * DH;
        if (which == 0)
          C[base + (size_t)s * DH + d] = v;
        else if (which == 1)
          C[base + (size_t)(s >> 5) * 4096 + (d >> 3) * 256 + (s & 31) * 8 + (d & 7)] = v;
        else
          C[base + (size_t)(s >> 3) * 1024 + d * 8 + (s & 7)] = v;
      }
}

// ---------------------------------------------------------------------------
// O-projection: C(f32)[4096][2048] = A_bf16 @ Wo_bf16^T. grid (8, 32).
// ---------------------------------------------------------------------------
__global__ __launch_bounds__(512) void gemm_out_pipe(
    const unsigned short* __restrict__ A, const unsigned short* __restrict__ W,
    float* __restrict__ C) {
  __shared__ __align__(16) char SM[147456];
  const int tid = threadIdx.x;
  const int lane = tid & 63, wv = tid >> 6;
  const int wr = wv >> 2, wc = wv & 3;
  const int g = lane >> 4, lr = lane & 15;
  const int m0 = blockIdx.y * 128, n0 = blockIdx.x * 256;

  PIPE_SETUP(A, W)

  f32x4 acc[4][4];
#pragma unroll
  for (int i = 0; i < 4; ++i)
#pragma unroll
    for (int j = 0; j < 4; ++j) acc[i][j] = (f32x4){0.f, 0.f, 0.f, 0.f};

  PIPE_PROLOGUE()
  PIPE_LOOP()

#pragma unroll
  for (int mi = 0; mi < 4; ++mi)
#pragma unroll
    for (int ni = 0; ni < 4; ++ni)
#pragma unroll
      for (int r = 0; r < 4; ++r) {
        const int row = m0 + wr * 64 + mi * 16 + g * 4 + r;
        const int col = n0 + wc * 64 + ni * 16 + lr;
        C[(size_t)row * HIDDEN + col] = acc[mi][ni][r];
      }
}

// ---------------------------------------------------------------------------
// MFMA flash attention, occupancy rework: QBLK=64 -> 1024 blocks, 256 thr /
// 4 waves, each wave ONE 16-row m-block. 2-slot K/V ring (LDS 37 KB ->
// 4 blocks/CU = 16 waves/CU; the vmcnt(0)+raw-barrier drain per tile is
// hidden by sibling blocks, m114). K blocked [S/32][d/8][s%32][8], V blocked
// [S/8][D][8] -> tile staging = 2 contiguous 8KB gll16 groups. Log2-domain
// softmax, defer-max THR=8, per-lane deferred l-sum, setprio, head-aligned
// XCD grid (bid&31 = bh).
// ---------------------------------------------------------------------------
__global__ __launch_bounds__(256, 4) void attn_mfma(const unsigned short* __restrict__ Q,
                                                    const unsigned short* __restrict__ K,
                                                    const unsigned short* __restrict__ V,
                                                    unsigned short* __restrict__ Ab) {
  const int bid = blockIdx.x;
  const int bh = bid & 31;            // bid%8 == bh%8 -> head-aligned XCD
  const int q0 = (bid >> 5) * 64;
  const int tid = threadIdx.x;
  const int wv = tid >> 6, lane = tid & 63;
  const int g = lane >> 4, lr = lane & 15;
  const unsigned short* Qh = Q + (size_t)bh * SEQ * DH;
  const unsigned short* Kh = K + (size_t)bh * SEQ * DH;
  const unsigned short* Vh = V + (size_t)bh * SEQ * DH;

  __shared__ __align__(16) unsigned short Kls[2][4096];
  __shared__ __align__(16) unsigned short Vls[2][4096];
  __shared__ __align__(16) unsigned short Pw[4][16][40];

  bf16x8 qf[4];
#pragma unroll
  for (int kb = 0; kb < 4; ++kb)
    qf[kb] = *(const bf16x8*)&Qh[(size_t)(q0 + wv * 16 + lr) * DH + kb * 32 + g * 8];

  f32x4 acc[8];
#pragma unroll
  for (int dn = 0; dn < 8; ++dn) acc[dn] = (f32x4){0.f, 0.f, 0.f, 0.f};
  float mrun = -1e30f;
  float lrun = 0.f;

  // prologue: stage tile 0 into slot 0
#pragma unroll
  for (int j = 0; j < 2; ++j) {
    const int c = j * 256 + tid;
    gll16(Kh + (size_t)c * 8, (char*)&Kls[0][0] + j * 4096 + wv * 1024);
    gll16(Vh + (size_t)c * 8, (char*)&Vls[0][0] + j * 4096 + wv * 1024);
  }

  for (int t = 0; t < 64; ++t) {
    const int cur = t & 1;
    asm volatile("s_waitcnt vmcnt(0)" ::: "memory");
    __builtin_amdgcn_s_barrier();   // separates slot reads (t-1) from writes (t+1)
    if (t + 1 < 64) {
      const unsigned short* Kn = Kh + (size_t)(t + 1) * 4096;
      const unsigned short* Vn = Vh + (size_t)(t + 1) * 4096;
      char* kd = (char*)&Kls[cur ^ 1][0];
      char* vd = (char*)&Vls[cur ^ 1][0];
#pragma unroll
      for (int j = 0; j < 2; ++j) {
        const int c = j * 256 + tid;
        gll16(Kn + (size_t)c * 8, kd + j * 4096 + wv * 1024);
        gll16(Vn + (size_t)c * 8, vd + j * 4096 + wv * 1024);
      }
    }

    const char* Kc = (const char*)&Kls[cur][0];
    const char* Vc = (const char*)&Vls[cur][0];

    f32x4 st0 = (f32x4){0.f, 0.f, 0.f, 0.f};
    f32x4 st1 = (f32x4){0.f, 0.f, 0.f, 0.f};
    __builtin_amdgcn_s_setprio(1);
#pragma unroll
    for (int kb = 0; kb < 4; ++kb) {
      const int cb = (kb * 4 + g) * 32;
      bf16x8 kf0 = *(const bf16x8*)(Kc + (cb + lr) * 16);
      bf16x8 kf1 = *(const bf16x8*)(Kc + (cb + 16 + lr) * 16);
      st0 = mfma16(kf0, qf[kb], st0);
      st1 = mfma16(kf1, qf[kb], st1);
    }
    __builtin_amdgcn_s_setprio(0);
    float mt = fmaxf(fmaxf(fmaxf(st0[0], st0[1]), fmaxf(st0[2], st0[3])),
                     fmaxf(fmaxf(st1[0], st1[1]), fmaxf(st1[2], st1[3])));
    mt = fmaxf(mt, __shfl_xor(mt, 16));
    mt = fmaxf(mt, __shfl_xor(mt, 32));
    if (!__all(mt <= mrun + 8.0f)) {  // rare rescale (defer-max)
      const float mnew = fmaxf(mrun, mt);
      const float corr = __builtin_amdgcn_exp2f(mrun - mnew);
      lrun *= corr;
      mrun = mnew;
      const f32x4 cv = (f32x4){__shfl(corr, g * 4 + 0), __shfl(corr, g * 4 + 1),
                               __shfl(corr, g * 4 + 2), __shfl(corr, g * 4 + 3)};
#pragma unroll
      for (int dn = 0; dn < 8; ++dn) acc[dn] *= cv;
    }
    float p[8], ls = 0.f;
#pragma unroll
    for (int r = 0; r < 4; ++r) {
      p[r] = __builtin_amdgcn_exp2f(st0[r] - mrun);
      p[4 + r] = __builtin_amdgcn_exp2f(st1[r] - mrun);
      ls += p[r] + p[4 + r];
    }
    lrun += ls;  // per-lane partial; cross-lane reduce deferred to end
    uint2 pk0, pk1;
    pk0.x = cvtpk(p[0], p[1]); pk0.y = cvtpk(p[2], p[3]);
    pk1.x = cvtpk(p[4], p[5]); pk1.y = cvtpk(p[6], p[7]);
    *(uint2*)&Pw[wv][lr][4 * g] = pk0;
    *(uint2*)&Pw[wv][lr][16 + 4 * g] = pk1;
    bf16x8 ap = *(const bf16x8*)&Pw[wv][lr][8 * g];
    // PV
    __builtin_amdgcn_s_setprio(1);
#pragma unroll
    for (int dn = 0; dn < 8; ++dn) {
      bf16x8 vf = *(const bf16x8*)(Vc + (g * 128 + dn * 16 + lr) * 16);
      acc[dn] = mfma16(ap, vf, acc[dn]);
    }
    __builtin_amdgcn_s_setprio(0);
  }

  const int b = bh >> 4, h = bh & 15;
  lrun += __shfl_xor(lrun, 16);
  lrun += __shfl_xor(lrun, 32);
  const float inv = 1.f / lrun;
  float ir[4];
#pragma unroll
  for (int r = 0; r < 4; ++r) ir[r] = __shfl(inv, g * 4 + r);
#pragma unroll
  for (int dn = 0; dn < 8; ++dn)
#pragma unroll
    for (int r = 0; r < 4; ++r) {
      const int srow = q0 + wv * 16 + g * 4 + r;
      Ab[((size_t)(b * SEQ + srow) * NHEADS + h) * DH + dn * 16 + lr] =
          f2bf(acc[dn][r] * ir[r]);
    }
}

// ---------------------------------------------------------------------------
extern "C" void kernel_launch(void* const* d_in, const int* in_sizes, int n_in,
                              void* d_out, int out_size, void* d_ws,
                              size_t ws_size, hipStream_t stream) {
  const float* X  = (const float*)d_in[0];
  const float* Wq = (const float*)d_in[1];
  const float* Wk = (const float*)d_in[2];
  const float* Wv = (const float*)d_in[3];
  const float* Wo = (const float*)d_in[4];
  float* out = (float*)d_out;

  const int n1 = MTOT * HIDDEN;    // 8388608
  const int n2 = HIDDEN * HIDDEN;  // 4194304

  char* p = (char*)d_ws;
  unsigned short* Xb  = (unsigned short*)(p + 0);          // 16 MB
  unsigned short* Qb  = (unsigned short*)(p + 16777216);   // 16 MB
  unsigned short* Kb  = (unsigned short*)(p + 33554432);   // 16 MB
  unsigned short* Vb  = (unsigned short*)(p + 50331648);   // 16 MB
  unsigned short* Wqb = (unsigned short*)(p + 67108864);   // 8 MB
  unsigned short* Wkb = (unsigned short*)(p + 75497472);   // 8 MB
  unsigned short* Wvb = (unsigned short*)(p + 83886080);   // 8 MB
  unsigned short* Wob = (unsigned short*)(p + 92274688);   // 8 MB
  unsigned short* Ab  = (unsigned short*)(p + 100663296);  // 16 MB (ends 117440512)

  cast_all<<<(n1 + 4 * n2) / 1024, 256, 0, stream>>>(X, Wq, Wk, Wv, Wo, Xb, Wqb,
                                                     Wkb, Wvb, Wob);

  gemm_qkv_pipe<<<dim3(24, MTOT / 128), 512, 0, stream>>>(Xb, Wqb, Wkb, Wvb,
                                                          Qb, Kb, Vb);

  attn_mfma<<<dim3(1024), 256, 0, stream>>>(Qb, Kb, Vb, Ab);

  gemm_out_pipe<<<dim3(HIDDEN / 256, MTOT / 128), 512, 0, stream>>>(Ab, Wob, out);
}